// Round 1
// baseline (26063.358 us; speedup 1.0000x reference)
//
#include <hip/hip_runtime.h>

// ---------------------------------------------------------------------------
// LSTM  T=2048, B=256, IN=64, H=256  (gates 4H=1024)
// Structure: sync-free persistent kernel. 16 workgroups x 512 threads; each
// workgroup owns 16 batch samples for ALL 2048 timesteps (only __syncthreads
// between steps -- no inter-workgroup communication at all).
// Weights are repacked once per launch into bf16 MFMA B-fragments in d_ws and
// streamed from L2 every step (640KB/step/CU = expected bottleneck).
// A-operand (x_t | h_{t-1}) is split hi/lo bf16 to suppress compounding
// recurrent rounding error; B-fragments are reused for both halves.
// ---------------------------------------------------------------------------

#define T_SEQ 2048
#define B_SZ  256
#define IN_SZ 64
#define H_SZ  256
#define G4    1024            // 4*H
#define NKF   10              // K-fragments: (IN+H)/32 = 320/32
#define NCT   64              // col tiles: G4/16
#define BB    16              // batch rows per workgroup
#define NWG   16              // B_SZ/BB
#define LDS_K 648             // 2*(IN+H) + 8 pad (shorts per row)
#define FRAG_BYTES (NCT * NKF * 64 * 16)   // 655360 B of bf16 B-fragments

typedef float f32x4 __attribute__((ext_vector_type(4)));
typedef short s16x8 __attribute__((ext_vector_type(8)));
typedef short s16x2 __attribute__((ext_vector_type(2)));

__device__ __forceinline__ short f2bf(float f) {          // RNE f32->bf16 bits
    unsigned u = __builtin_bit_cast(unsigned, f);
    u = u + 0x7fffu + ((u >> 16) & 1u);
    return (short)(u >> 16);
}
__device__ __forceinline__ float bf2f(short s) {
    return __builtin_bit_cast(float, ((unsigned)(unsigned short)s) << 16);
}
__device__ __forceinline__ float fsigmoid(float v) {
    return __builtin_amdgcn_rcpf(1.0f + __expf(-v));
}
__device__ __forceinline__ float ftanh(float v) {
    return 2.0f * __builtin_amdgcn_rcpf(1.0f + __expf(-2.0f * v)) - 1.0f;
}

// --- repack Wx|Wh (fp32, [k][n] row-major) into bf16 MFMA B-fragments ------
// Logical k slot convention (must only be consistent between A and B frags):
//   fragment (ct,kf), lane l, elem j  <->  k = kf*32 + (l>>4)*8 + j,
//                                          n = ct*16 + (l&15)
__global__ void repack_kernel(const float* __restrict__ Wx,
                              const float* __restrict__ Wh,
                              const float* __restrict__ bx,
                              const float* __restrict__ bh,
                              s16x8* __restrict__ fragbuf,
                              float* __restrict__ bias) {
    const int blk  = blockIdx.x;          // ct*NKF + kf, 0..639
    const int lane = threadIdx.x;         // 0..63
    const int ct = blk / NKF;
    const int kf = blk - ct * NKF;
    const int n  = ct * 16 + (lane & 15);
    const int q  = lane >> 4;
    s16x8 frag;
#pragma unroll
    for (int j = 0; j < 8; ++j) {
        const int k = kf * 32 + q * 8 + j;
        const float v = (k < IN_SZ) ? Wx[k * G4 + n] : Wh[(k - IN_SZ) * G4 + n];
        frag[j] = f2bf(v);
    }
    fragbuf[blk * 64 + lane] = frag;
    if (blk < 16) {                        // 16*64 = 1024 bias entries
        const int i = blk * 64 + lane;
        bias[i] = bx[i] + bh[i];
    }
}

// --- persistent recurrence kernel ------------------------------------------
// LDS A-tile: [16 rows(samples)][LDS_K shorts]:
//   k in [0,64)    : x_t hi      k in [64,320)  : h hi
//   k in [320,384) : x_t lo      k in [384,640) : h lo
__global__ __launch_bounds__(512) void lstm_persist(
        const float* __restrict__ x,
        const s16x8* __restrict__ fragbuf,
        const float* __restrict__ bias,
        float* __restrict__ out) {
    __shared__ short lds_a[16 * LDS_K];

    const int tid  = threadIdx.x;
    const int lane = tid & 63;
    const int w    = tid >> 6;            // wave 0..7
    const int q    = lane >> 4;
    const int ln   = lane & 15;
    const int S    = blockIdx.x * BB;     // sample base of this workgroup

    for (int i = tid; i < 16 * LDS_K; i += 512) lds_a[i] = 0;

    // wave w owns col-tiles ct = w + 8*ci  (ci=0..7):
    //   ci 0,1 -> f gate;  2,3 -> i;  4,5 -> o;  6,7 -> g
    //   ci even -> hidden block w, ci odd -> hidden block w+8
    float bias_r[8];
#pragma unroll
    for (int ci = 0; ci < 8; ++ci) bias_r[ci] = bias[(w + 8 * ci) * 16 + ln];

    f32x4 cst0 = {0.f, 0.f, 0.f, 0.f};    // c state, hidden block w
    f32x4 cst1 = {0.f, 0.f, 0.f, 0.f};    // c state, hidden block w+8

    const int xrow = tid >> 5;            // 0..15 (sample row)
    const int xi   = (tid & 31) << 1;     // 0..62 (input feature pair)

    __syncthreads();

    const float* xp0   = x   + (size_t)(S + xrow) * IN_SZ + xi;
    float*       outp0 = out + (size_t)S * H_SZ;

    for (int t = 0; t < T_SEQ; ++t) {
        // ---- phase 1: stage x_t (hi/lo bf16) into LDS ----
        {
            const float* xp = xp0 + (size_t)t * (B_SZ * IN_SZ);
            const float v0 = xp[0], v1 = xp[1];
            const short h0 = f2bf(v0), h1 = f2bf(v1);
            const short l0 = f2bf(v0 - bf2f(h0));
            const short l1 = f2bf(v1 - bf2f(h1));
            s16x2 hv = {h0, h1}, lv = {l0, l1};
            *reinterpret_cast<s16x2*>(&lds_a[xrow * LDS_K + xi])        = hv;
            *reinterpret_cast<s16x2*>(&lds_a[xrow * LDS_K + 320 + xi])  = lv;
        }
        __syncthreads();   // x staged; h region holds h_{t-1}

        // ---- phase 2: load A fragments (hi and lo) ----
        s16x8 ahi[NKF], alo[NKF];
#pragma unroll
        for (int kf = 0; kf < NKF; ++kf) {
            ahi[kf] = *reinterpret_cast<const s16x8*>(
                          &lds_a[ln * LDS_K + kf * 32 + q * 8]);
            alo[kf] = *reinterpret_cast<const s16x8*>(
                          &lds_a[ln * LDS_K + 320 + kf * 32 + q * 8]);
        }
        __syncthreads();   // all reads done; h region may be overwritten

        // ---- phase 3: gates = bias + [x|h]_hi @ W + [x|h]_lo @ W ----
        f32x4 acc[8];
#pragma unroll
        for (int ci = 0; ci < 8; ++ci) {
            const int ct = w + 8 * ci;
            f32x4 a = {bias_r[ci], bias_r[ci], bias_r[ci], bias_r[ci]};
            const s16x8* bp = fragbuf + (size_t)ct * NKF * 64 + lane;
#pragma unroll
            for (int kf = 0; kf < NKF; ++kf) {
                const s16x8 b = bp[kf * 64];   // streamed from L2 every step
                a = __builtin_amdgcn_mfma_f32_16x16x32_bf16(ahi[kf], b, a, 0, 0, 0);
                a = __builtin_amdgcn_mfma_f32_16x16x32_bf16(alo[kf], b, a, 0, 0, 0);
            }
            acc[ci] = a;
        }

        // ---- phase 4: LSTM cell + writes ----
        // C/D layout (m89-verified): col = lane&15, row = (lane>>4)*4 + reg
        float* outp = outp0 + (size_t)t * (B_SZ * H_SZ);
        const bool last = (t == T_SEQ - 1);
#pragma unroll
        for (int p = 0; p < 2; ++p) {
            const int hcol = (w + 8 * p) * 16 + ln;
            f32x4& cs = p ? cst1 : cst0;
            const f32x4 fg = acc[p],     ig = acc[2 + p];
            const f32x4 og = acc[4 + p], gg = acc[6 + p];
#pragma unroll
            for (int r = 0; r < 4; ++r) {
                const float cf = fsigmoid(fg[r]) * cs[r]
                               + fsigmoid(ig[r]) * ftanh(gg[r]);
                const float hv = fsigmoid(og[r]) * ftanh(cf);
                cs[r] = cf;
                const int m = q * 4 + r;
                outp[m * H_SZ + hcol] = hv;                 // h_seq (fp32)
                const short hh = f2bf(hv);
                const short hl = f2bf(hv - bf2f(hh));
                lds_a[m * LDS_K + 64  + hcol] = hh;         // h hi for t+1
                lds_a[m * LDS_K + 384 + hcol] = hl;         // h lo for t+1
                if (last) {
                    float* fin = out + (size_t)T_SEQ * B_SZ * H_SZ;
                    fin[(S + m) * H_SZ + hcol] = hv;                    // h
                    fin[B_SZ * H_SZ + (S + m) * H_SZ + hcol] = cf;      // c
                }
            }
        }
        // no sync needed here: next phase-1 writes x region (disjoint from h),
        // and the top-of-loop __syncthreads orders h writes vs phase-2 reads.
    }
}

extern "C" void kernel_launch(void* const* d_in, const int* in_sizes, int n_in,
                              void* d_out, int out_size, void* d_ws, size_t ws_size,
                              hipStream_t stream) {
    const float* x  = (const float*)d_in[0];
    const float* Wx = (const float*)d_in[1];
    const float* Wh = (const float*)d_in[2];
    const float* bx = (const float*)d_in[3];
    const float* bh = (const float*)d_in[4];
    float* out = (float*)d_out;

    s16x8* fragbuf = (s16x8*)d_ws;                         // 655360 B
    float* bias    = (float*)((char*)d_ws + FRAG_BYTES);   // + 4096 B

    repack_kernel<<<NCT * NKF, 64, 0, stream>>>(Wx, Wh, bx, bh, fragbuf, bias);
    lstm_persist<<<NWG, 512, 0, stream>>>(x, fragbuf, bias, out);
}

// Round 4
// 12571.052 us; speedup vs baseline: 2.0733x; 2.0733x over previous
//
#include <hip/hip_runtime.h>

// ---------------------------------------------------------------------------
// LSTM T=2048, B=256, IN=64, H=256 (gates 4H=1024)
// R2b: weights fully register-resident. 16 sample-groups x 2 WGs (column
// halves) = 32 WGs x 512 threads. Each wave owns ONE 16-col hidden block
// (f,i,o,g col-tiles) -> 40 bf16 B-fragments = 160 VGPRs, loaded once.
// Per step the 2 team WGs exchange 128-col h-slices via LLC:
//   producer: two 8B write-through (agent atomic) stores/lane, [col][sample]
//   consumer: relaxed spin -> acquire fence -> ONE coalesced dwordx4/thread
//             -> unpack into the LDS A-matrix peer region.
// x prefetched one step ahead; hi/lo-split bf16 A with split acc chains.
// ---------------------------------------------------------------------------

#define T_SEQ 2048
#define B_SZ  256
#define IN_SZ 64
#define H_SZ  256
#define G4    1024
#define NKF   10              // K fragments: (IN+H)/32
#define NCT   64              // col tiles: 4H/16
#define LDSK  648             // shorts per sample row: 2*(IN+H)+8 pad
#define FRAG_BYTES (NCT * NKF * 64 * 16)      // 655360 B
#define BIAS_OFF   FRAG_BYTES                 // 1024 floats
#define FLAGS_OFF  (FRAG_BYTES + 4096)        // 32 u32
#define XBUF_OFF   (FRAG_BYTES + 8192)        // 32 wg * 2 slots * 8KB = 512KB

typedef float f32x4 __attribute__((ext_vector_type(4)));
typedef short s16x8 __attribute__((ext_vector_type(8)));
typedef short s16x2 __attribute__((ext_vector_type(2)));
typedef unsigned u32x4 __attribute__((ext_vector_type(4)));

__device__ __forceinline__ short f2bf(float f) {          // RNE f32->bf16
    unsigned u = __builtin_bit_cast(unsigned, f);
    u = u + 0x7fffu + ((u >> 16) & 1u);
    return (short)(u >> 16);
}
__device__ __forceinline__ float bf2f(short s) {
    return __builtin_bit_cast(float, ((unsigned)(unsigned short)s) << 16);
}
__device__ __forceinline__ float fsigmoid(float v) {
    return __builtin_amdgcn_rcpf(1.0f + __expf(-v));
}
__device__ __forceinline__ float ftanh(float v) {
    return 2.0f * __builtin_amdgcn_rcpf(1.0f + __expf(-2.0f * v)) - 1.0f;
}

// --- repack Wx|Wh into bf16 MFMA B-fragments -------------------------------
// fragment (ct,kf), lane l, elem j <-> k = kf*32 + (l>>4)*8 + j, n = ct*16+(l&15)
__global__ void repack_kernel(const float* __restrict__ Wx,
                              const float* __restrict__ Wh,
                              const float* __restrict__ bx,
                              const float* __restrict__ bh,
                              s16x8* __restrict__ fragbuf,
                              float* __restrict__ bias) {
    const int blk  = blockIdx.x;          // ct*NKF + kf
    const int lane = threadIdx.x;
    const int ct = blk / NKF;
    const int kf = blk - ct * NKF;
    const int n  = ct * 16 + (lane & 15);
    const int q  = lane >> 4;
    s16x8 frag;
#pragma unroll
    for (int j = 0; j < 8; ++j) {
        const int k = kf * 32 + q * 8 + j;
        const float v = (k < IN_SZ) ? Wx[k * G4 + n] : Wh[(k - IN_SZ) * G4 + n];
        frag[j] = f2bf(v);
    }
    fragbuf[blk * 64 + lane] = frag;
    if (blk < 16) {
        const int i = blk * 64 + lane;
        bias[i] = bx[i] + bh[i];
    }
}

__global__ void init_flags(unsigned* __restrict__ flags) {
    if (threadIdx.x < 32) flags[threadIdx.x] = 0u;
}

// --- persistent recurrence kernel ------------------------------------------
// LDS: double-buffered A matrix [2][16 samples][LDSK shorts]
//   k in [0,64): x hi   [64,320): h hi   [320,384): x lo   [384,640): h lo
__global__ __launch_bounds__(512, 2) void lstm_persist(
        const float* __restrict__ x,
        const s16x8* __restrict__ fragbuf,
        const float* __restrict__ bias,
        float* __restrict__ out,
        unsigned* __restrict__ flags,
        unsigned* __restrict__ xbuf) {
    __shared__ short lds_a[2 * 16 * LDSK];

    const int tid  = threadIdx.x;
    const int lane = tid & 63;
    const int w    = tid >> 6;            // wave 0..7
    const int q    = lane >> 4;
    const int ln   = lane & 15;
    const int bid  = blockIdx.x;
    const int g    = bid >> 1;            // sample group 0..15
    const int p    = bid & 1;             // column half (0:lo cols, 1:hi cols)
    const int peer = bid ^ 1;
    const int S    = g * 16;              // sample base
    const int hb   = p * 8 + w;           // hidden block 0..15
    const int col  = hb * 16 + ln;        // this lane's h column (global)

    for (int i = tid; i < 2 * 16 * LDSK; i += 512) lds_a[i] = 0;

    // ---- weights into registers: wt[ci][j], ci=gate(f,i,o,g)
    // j order: 0,1 -> x; 2..5 -> OWN h half; 6..9 -> PEER h half
    s16x8 wt[4][10];
#pragma unroll
    for (int ci = 0; ci < 4; ++ci) {
        const int ct = ci * 16 + hb;
#pragma unroll
        for (int j = 0; j < 10; ++j) {
            const int kf = (j < 2) ? j
                         : (j < 6 ? 2 + 4 * p + (j - 2)
                                  : 2 + 4 * (1 - p) + (j - 6));
            wt[ci][j] = fragbuf[(size_t)(ct * NKF + kf) * 64 + lane];
        }
    }
    float bs[4];
#pragma unroll
    for (int ci = 0; ci < 4; ++ci) bs[ci] = bias[(ci * 16 + hb) * 16 + ln];

    f32x4 cs = {0.f, 0.f, 0.f, 0.f};      // cell state rows q*4+r, col

    // x prefetch (one step ahead, held in regs)
    const int xrow = tid >> 5;            // 0..15
    const int xi   = (tid & 31) << 1;     // 0..62
    const float* xp0 = x + (size_t)(S + xrow) * IN_SZ + xi;
    float xv0 = xp0[0], xv1 = xp0[1];

    __syncthreads();

    for (int t = 0; t < T_SEQ; ++t) {
        const int cur = t & 1;
        short* L  = lds_a + cur * (16 * LDSK);        // A of step t
        short* Ln = lds_a + (1 - cur) * (16 * LDSK);  // h destination (t)

        // ---- stage x_t from prefetched regs (hi/lo) ----
        {
            const short h0 = f2bf(xv0), h1 = f2bf(xv1);
            const short l0 = f2bf(xv0 - bf2f(h0));
            const short l1 = f2bf(xv1 - bf2f(h1));
            s16x2 hv = {h0, h1}, lv = {l0, l1};
            *reinterpret_cast<s16x2*>(&L[xrow * LDSK + xi])       = hv;
            *reinterpret_cast<s16x2*>(&L[xrow * LDSK + 320 + xi]) = lv;
        }
        // ---- issue x_{t+1} prefetch (latency hidden behind step) ----
        {
            const int tn = (t + 1 < T_SEQ) ? t + 1 : t;
            const float* xp = xp0 + (size_t)tn * (B_SZ * IN_SZ);
            xv0 = xp[0]; xv1 = xp[1];
        }

        // ---- peer h slice: spin, fence, ONE dwordx4/thread, unpack to LDS --
        if (t > 0) {
            while (__hip_atomic_load(&flags[peer], __ATOMIC_RELAXED,
                                     __HIP_MEMORY_SCOPE_AGENT) < (unsigned)t) {
                __builtin_amdgcn_s_sleep(1);
            }
            __builtin_amdgcn_fence(__ATOMIC_ACQUIRE, "agent");
            const u32x4* ps = (const u32x4*)(xbuf
                              + (size_t)(peer * 2 + ((t - 1) & 1)) * 2048);
            const u32x4 v = ps[tid];          // u32s [4t .. 4t+3]
            const int colp = tid >> 2;        // 0..127 within peer half
            const int cg   = 128 * (1 - p) + colp;
            const int m0   = (tid & 3) * 4;
#pragma unroll
            for (int e = 0; e < 4; ++e) {
                const unsigned u = v[e];
                const int m = m0 + e;
                L[m * LDSK + 64  + cg] = (short)(u & 0xffffu);
                L[m * LDSK + 384 + cg] = (short)(u >> 16);
            }
        }
        __syncthreads();

        // ---- MFMAs: 10 j x 4 gates x (hi,lo), split acc chains ----
        f32x4 acc[4], acl[4];
#pragma unroll
        for (int ci = 0; ci < 4; ++ci) {
            acc[ci] = (f32x4){bs[ci], bs[ci], bs[ci], bs[ci]};
            acl[ci] = (f32x4){0.f, 0.f, 0.f, 0.f};
        }
#pragma unroll
        for (int j = 0; j < 10; ++j) {
            const int kf = (j < 2) ? j
                         : (j < 6 ? 2 + 4 * p + (j - 2)
                                  : 2 + 4 * (1 - p) + (j - 6));
            const s16x8 ah = *reinterpret_cast<const s16x8*>(
                                 &L[ln * LDSK + kf * 32 + q * 8]);
            const s16x8 al = *reinterpret_cast<const s16x8*>(
                                 &L[ln * LDSK + 320 + kf * 32 + q * 8]);
#pragma unroll
            for (int ci = 0; ci < 4; ++ci) {
                acc[ci] = __builtin_amdgcn_mfma_f32_16x16x32_bf16(ah, wt[ci][j], acc[ci], 0, 0, 0);
                acl[ci] = __builtin_amdgcn_mfma_f32_16x16x32_bf16(al, wt[ci][j], acl[ci], 0, 0, 0);
            }
        }
#pragma unroll
        for (int ci = 0; ci < 4; ++ci) acc[ci] += acl[ci];

        // ---- cell update + outputs + publish ----
        // C/D layout (m89): col = lane&15, row = (lane>>4)*4 + r
        float* hs = out + (size_t)t * (B_SZ * H_SZ) + (size_t)S * H_SZ;
        unsigned* os = xbuf + (size_t)(bid * 2 + cur) * 2048;
        const bool last = (t == T_SEQ - 1);
        unsigned pu[4];
#pragma unroll
        for (int r = 0; r < 4; ++r) {
            const float fv = fsigmoid(acc[0][r]);
            const float iv = fsigmoid(acc[1][r]);
            const float ov = fsigmoid(acc[2][r]);
            const float gv = ftanh(acc[3][r]);
            const float cf = fv * cs[r] + iv * gv;
            cs[r] = cf;
            const float hv = ov * ftanh(cf);
            const int m = q * 4 + r;
            __builtin_nontemporal_store(hv, hs + m * H_SZ + col);   // h_seq
            const short hh = f2bf(hv);
            const short hl = f2bf(hv - bf2f(hh));
            Ln[m * LDSK + 64  + col] = hh;                          // h hi (t)
            Ln[m * LDSK + 384 + col] = hl;                          // h lo (t)
            pu[r] = ((unsigned)(unsigned short)hh)
                  | (((unsigned)(unsigned short)hl) << 16);
            if (last) {
                float* fin = out + (size_t)T_SEQ * B_SZ * H_SZ;
                fin[(S + m) * H_SZ + col] = hv;                     // final h
                fin[B_SZ * H_SZ + (S + m) * H_SZ + col] = cf;       // final c
            }
        }
        // publish layout: os[colp*16 + m]  (colp = within-half col)
        {
            const int colp = w * 16 + ln;
            unsigned long long* od =
                (unsigned long long*)(os + colp * 16 + q * 4);
            const unsigned long long u01 =
                (unsigned long long)pu[0] | ((unsigned long long)pu[1] << 32);
            const unsigned long long u23 =
                (unsigned long long)pu[2] | ((unsigned long long)pu[3] << 32);
            __hip_atomic_store(&od[0], u01, __ATOMIC_RELAXED,
                               __HIP_MEMORY_SCOPE_AGENT);
            __hip_atomic_store(&od[1], u23, __ATOMIC_RELAXED,
                               __HIP_MEMORY_SCOPE_AGENT);
        }
        __syncthreads();   // drains vmcnt: publish stores complete (sc1/WT)
        if (tid == 0)
            __hip_atomic_store(&flags[bid], (unsigned)(t + 1),
                               __ATOMIC_RELEASE, __HIP_MEMORY_SCOPE_AGENT);
    }
}

extern "C" void kernel_launch(void* const* d_in, const int* in_sizes, int n_in,
                              void* d_out, int out_size, void* d_ws, size_t ws_size,
                              hipStream_t stream) {
    const float* x  = (const float*)d_in[0];
    const float* Wx = (const float*)d_in[1];
    const float* Wh = (const float*)d_in[2];
    const float* bx = (const float*)d_in[3];
    const float* bh = (const float*)d_in[4];
    float* out = (float*)d_out;

    s16x8*    fragbuf = (s16x8*)d_ws;
    float*    bias    = (float*)((char*)d_ws + BIAS_OFF);
    unsigned* flags   = (unsigned*)((char*)d_ws + FLAGS_OFF);
    unsigned* xbuf    = (unsigned*)((char*)d_ws + XBUF_OFF);

    repack_kernel<<<NCT * NKF, 64, 0, stream>>>(Wx, Wh, bx, bh, fragbuf, bias);
    init_flags<<<1, 64, 0, stream>>>(flags);
    lstm_persist<<<32, 512, 0, stream>>>(x, fragbuf, bias, out, flags, xbuf);
}